// Round 15
// baseline (733.233 us; speedup 1.0000x reference)
//
#include <hip/hip_runtime.h>
#include <cstddef>

#define N_NODES 100000
#define E_EDGES 1600000
#define NFEAT   602
#define NHID    128
#define NCLASS  41
#define LN_EPS  1e-5f

typedef __bf16 bf16x8 __attribute__((ext_vector_type(8)));
typedef float f32x4 __attribute__((ext_vector_type(4)));
typedef unsigned short ushort8 __attribute__((ext_vector_type(8)));
typedef int intx4 __attribute__((ext_vector_type(4)));

__device__ inline float bflo(unsigned int u) {
    return __builtin_bit_cast(float, u << 16);
}
__device__ inline float bfhi(unsigned int u) {
    return __builtin_bit_cast(float, u & 0xFFFF0000u);
}
__device__ inline unsigned short f2bf(float f) {
    return __builtin_bit_cast(unsigned short, (__bf16)f);
}

#define NT1 19   // ceil(602/32)
#define NT2 4    // 128/32

// ---------------------------------------------------------------------------
// Pre-swizzle all three W matrices into MFMA B-fragment layout (bf16).
// ---------------------------------------------------------------------------
__global__ __launch_bounds__(256) void k_prep_all(
    const float* __restrict__ W1, const float* __restrict__ W2,
    const float* __restrict__ W3, unsigned short* __restrict__ Wf1,
    unsigned short* __restrict__ Wf2, unsigned short* __restrict__ Wf3)
{
    const int wid = (blockIdx.x * 256 + threadIdx.x) >> 6;
    const int lane = threadIdx.x & 63;
    const float* W; unsigned short* Wf; int K; int lw;
    if (wid < NT1 * 8)            { W = W1; Wf = Wf1; K = NFEAT; lw = wid; }
    else if (wid < (NT1 + NT2) * 8) { W = W2; Wf = Wf2; K = NHID; lw = wid - NT1 * 8; }
    else if (wid < (NT1 + 2 * NT2) * 8) { W = W3; Wf = Wf3; K = NHID; lw = wid - (NT1 + NT2) * 8; }
    else return;
    const int t = lw >> 3, n = lw & 7;
    const int fr = lane & 15, kh = lane >> 4;
    const int c = n * 16 + fr;
    ushort8 v;
#pragma unroll
    for (int j = 0; j < 8; ++j) {
        int k = t * 32 + kh * 8 + j;
        float x = (k < K) ? W[(size_t)k * 128 + c] : 0.f;
        v[j] = f2bf(x);
    }
    *reinterpret_cast<ushort8*>(Wf + ((size_t)lw * 64 + lane) * 8) = v;
}

// ---------------------------------------------------------------------------
// Slab GEMM: 512 threads stage a contiguous 64-row slab into LDS; 8 waves
// compute 16 rows x 64 cols each. (Proven, unchanged.)
// ---------------------------------------------------------------------------
template<int KK, bool BF16A>
__global__ __launch_bounds__(512) void k_gemm_slab(
    const void* __restrict__ Ain, const unsigned short* __restrict__ Wfrag,
    unsigned short* __restrict__ C, int M)
{
    constexpr int NT = (KK + 31) / 32;
    constexpr int KPAD = ((KK + 7) / 8) * 8 + 8;
    __shared__ unsigned short As[64 * KPAD + 8];

    const int tid = threadIdx.x;
    const int row0 = blockIdx.x * 64;
    const int nrow = (M - row0 < 64) ? (M - row0) : 64;
    const int total = nrow * KK;

    if (!BF16A) {
        const float* A32 = (const float*)Ain + (size_t)row0 * KK;
        constexpr int totalFull = 64 * KK;
#pragma unroll 4
        for (int base = 0; base < totalFull; base += 2048) {
            int i = base + tid * 4;
            if (i < totalFull) {
                float4 v = make_float4(0.f, 0.f, 0.f, 0.f);
                if (i + 4 <= total) {
                    v = *reinterpret_cast<const float4*>(A32 + i);
                } else if (i < total) {
                    float tmp[4] = {0.f, 0.f, 0.f, 0.f};
#pragma unroll
                    for (int e = 0; e < 4; ++e) if (i + e < total) tmp[e] = A32[i + e];
                    v = make_float4(tmp[0], tmp[1], tmp[2], tmp[3]);
                }
                int row = i / KK;
                int col = i - row * KK;
                unsigned int d0 = (unsigned int)f2bf(v.x) | ((unsigned int)f2bf(v.y) << 16);
                unsigned int d1 = (unsigned int)f2bf(v.z) | ((unsigned int)f2bf(v.w) << 16);
                int a0 = row * KPAD + col;
                int a1 = (col == KK - 2) ? (row + 1) * KPAD : a0 + 2;
                *reinterpret_cast<unsigned int*>(&As[a0]) = d0;
                *reinterpret_cast<unsigned int*>(&As[a1]) = d1;
            }
        }
    } else {
        const unsigned short* A16 = (const unsigned short*)Ain + (size_t)row0 * KK;
        constexpr int totalFull = 64 * KK;
#pragma unroll
        for (int base = 0; base < totalFull; base += 4096) {
            int i = base + tid * 8;
            if (i < totalFull) {
                ushort8 v;
#pragma unroll
                for (int j = 0; j < 8; ++j) v[j] = 0;
                if (i + 8 <= total) v = *reinterpret_cast<const ushort8*>(A16 + i);
                int row = i / KK;
                int col = i - row * KK;
                *reinterpret_cast<ushort8*>(&As[row * KPAD + col]) = v;
            }
        }
    }
    __syncthreads();

    const int wv = tid >> 6, lane = tid & 63;
    const int fr = lane & 15, kh = lane >> 4;
    const int mfr = wv >> 1;
    const int ch = wv & 1;
    const unsigned short* abase = &As[(mfr * 16 + fr) * KPAD + kh * 8];
    const unsigned short* wbase = Wfrag + ((size_t)(ch * 4) * 64 + lane) * 8;

    f32x4 acc[4];
#pragma unroll
    for (int n = 0; n < 4; ++n) acc[n] = (f32x4)(0.f);

    bf16x8 bcur[4];
#pragma unroll
    for (int n = 0; n < 4; ++n)
        bcur[n] = __builtin_bit_cast(bf16x8,
            *reinterpret_cast<const ushort8*>(wbase + n * 512));

#pragma unroll
    for (int t = 0; t < NT; ++t) {
        bf16x8 bnext[4];
        if (t + 1 < NT) {
            const unsigned short* wp = wbase + (size_t)(t + 1) * 4096;
#pragma unroll
            for (int n = 0; n < 4; ++n)
                bnext[n] = __builtin_bit_cast(bf16x8,
                    *reinterpret_cast<const ushort8*>(wp + n * 512));
        }
        bf16x8 af = *reinterpret_cast<const bf16x8*>(abase + t * 32);
        if (KK % 32 != 0 && t == NT - 1) {
#pragma unroll
            for (int j = 0; j < 8; ++j)
                if (t * 32 + kh * 8 + j >= KK) af[j] = (__bf16)0.f;
        }
#pragma unroll
        for (int n = 0; n < 4; ++n)
            acc[n] = __builtin_amdgcn_mfma_f32_16x16x32_bf16(af, bcur[n], acc[n], 0, 0, 0);
#pragma unroll
        for (int n = 0; n < 4; ++n) bcur[n] = bnext[n];
    }

#pragma unroll
    for (int jj = 0; jj < 4; ++jj) {
        int cr = row0 + mfr * 16 + kh * 4 + jj;
        if (cr < M) {
#pragma unroll
            for (int n = 0; n < 4; ++n)
                C[(size_t)cr * NHID + ch * 64 + n * 16 + fr] = f2bf(acc[n][jj]);
        }
    }
}

// ---------------------------------------------------------------------------
// Padded-CSR build: partition (no histogram) + per-graph padded scatter.
// Row r owns slots [r*DCAP, r*DCAP+fill[r]).
// ---------------------------------------------------------------------------
__global__ void k_zero(int* __restrict__ p, int n)
{
    int i = blockIdx.x * blockDim.x + threadIdx.x;
    if (i < n) p[i] = 0;
}

#define NBUCK 8
#define RPB   12500        // rows per bucket
#define CAP_G 210000       // stage capacity per (graph,bucket)
#define DCAP  48           // padded slots per row; P(deg>48) ~ 2e-11/row

// Phase A: LDS-binned partition with wave-ballot counter aggregation
// (R13-proven loop: every stride-256 iteration is a full wave since E and
// all chunk sizes are multiples of 256). 8 ballots + 8 leader LDS atomics
// per wave-iter instead of 64 serialized same-address RMWs.
#define PCHUNK 3072
#define BPG    ((E_EDGES + PCHUNK - 1) / PCHUNK)   // 521
#define BCAP   512

__global__ __launch_bounds__(256) void k_partition(
    const int* __restrict__ rows, const int* __restrict__ cols,
    const float* __restrict__ vals,
    int* __restrict__ cntA, intx4* __restrict__ stage)
{
    __shared__ int br[NBUCK * BCAP];
    __shared__ int bc[NBUCK * BCAP];
    __shared__ int bv[NBUCK * BCAP];
    __shared__ int bcnt[NBUCK];
    __shared__ int bbase[NBUCK];

    const int g = blockIdx.x / BPG;
    const int chunk = blockIdx.x - g * BPG;
    const int e0 = chunk * PCHUNK;
    const int e1 = (e0 + PCHUNK < E_EDGES) ? (e0 + PCHUNK) : E_EDGES;
    const int lane = threadIdx.x & 63;
    const int* rg = rows + (size_t)g * E_EDGES;
    const int* cg = cols + (size_t)g * E_EDGES;
    const float* vg = vals + (size_t)g * E_EDGES;

    if (threadIdx.x < NBUCK) bcnt[threadIdx.x] = 0;
    __syncthreads();

    for (int i = e0 + (int)threadIdx.x; i < e1; i += 256) {
        int r = rg[i];
        int c = cg[i];
        float v = vg[i];
        int b = r / RPB;
        int off = 0;
#pragma unroll
        for (int bb = 0; bb < NBUCK; ++bb) {
            unsigned long long mask = __ballot(b == bb);
            if (b == bb) {
                int leader = __ffsll((unsigned long long)mask) - 1;
                int base = 0;
                if (lane == leader)
                    base = atomicAdd(&bcnt[bb], (int)__popcll(mask));
                base = __shfl(base, leader);
                off = base + (int)__popcll(mask & ((1ull << lane) - 1ull));
            }
        }
        if (off < BCAP) {
            br[b * BCAP + off] = r;
            bc[b * BCAP + off] = c;
            bv[b * BCAP + off] = __builtin_bit_cast(int, v);
        } else {                                       // rare overflow
            int p = atomicAdd(&cntA[g * NBUCK + b], 1);
            intx4 e;
            e.x = r; e.y = c; e.z = __builtin_bit_cast(int, v); e.w = 0;
            stage[(size_t)(g * NBUCK + b) * CAP_G + p] = e;
        }
    }
    __syncthreads();

    if (threadIdx.x < NBUCK) {
        int n = bcnt[threadIdx.x];
        n = (n < BCAP) ? n : BCAP;
        bbase[threadIdx.x] = atomicAdd(&cntA[g * NBUCK + threadIdx.x], n);
        bcnt[threadIdx.x] = n;
    }
    __syncthreads();

#pragma unroll
    for (int b = 0; b < NBUCK; ++b) {
        int n = bcnt[b];
        int base = bbase[b];
        intx4* dst = stage + (size_t)(g * NBUCK + b) * CAP_G;
        for (int j = (int)threadIdx.x; j < n; j += 256) {
            intx4 e;
            e.x = br[b * BCAP + j];
            e.y = bc[b * BCAP + j];
            e.z = bv[b * BCAP + j];
            e.w = 0;
            dst[base + j] = e;
        }
    }
}

#define SLICES 256

// Phase B: per-graph padded scatter (proven). bucket = blockIdx&7 (XCD pin).
// fill[r] counts edges AND assigns the slot: ecv[r*DCAP + p].
__global__ __launch_bounds__(256) void k_scatter_l2(
    const intx4* __restrict__ stageG,   // stage + g*8*CAP_G
    const int* __restrict__ cntAG,      // cntA + g*8
    int* __restrict__ fillG,            // fill3 + g*N
    int2* __restrict__ ecvG)            // ecv3 + g*N*DCAP
{
    const int b = blockIdx.x & 7;
    const int slice = blockIdx.x >> 3;
    const int n = cntAG[b];
    const intx4* sp = stageG + (size_t)b * CAP_G;
    for (int i = slice * 256 + (int)threadIdx.x; i < n; i += SLICES * 256) {
        intx4 e = __builtin_nontemporal_load(sp + i);
        int p = atomicAdd(&fillG[e.x], 1);
        if (p < DCAP)
            ecvG[(size_t)e.x * DCAP + p] = make_int2(e.y, e.z);
    }
}

// ---------------------------------------------------------------------------
// Fused spmm (padded CSR gather, bf16 H) + bias + LayerNorm + ReLU.
// Row r's edges at [r*DCAP, r*DCAP + fill[r]). Unroll 8 (proven body).
// ---------------------------------------------------------------------------
__global__ __launch_bounds__(256) void k_spmm_ln(
    const unsigned short* __restrict__ Hin, const int* __restrict__ fillG,
    const int2* __restrict__ ecvG,
    const float* __restrict__ bias, const float* __restrict__ g,
    const float* __restrict__ bb, unsigned short* __restrict__ Hout)
{
    const int w = threadIdx.x >> 6;
    const int lane = threadIdx.x & 63;
    const int row = blockIdx.x * 4 + w;
    int cnt = fillG[row];
    cnt = (cnt < DCAP) ? cnt : DCAP;
    const int start = row * DCAP;
    const int end = start + cnt;
    const int2* ecv = ecvG;

    float a0 = 0.f, a1 = 0.f;
    int p = start;
    for (; p + 7 < end; p += 8) {
        int2 e[8];
        unsigned int h[8];
#pragma unroll
        for (int j = 0; j < 8; ++j) e[j] = ecv[p + j];
#pragma unroll
        for (int j = 0; j < 8; ++j)
            h[j] = *reinterpret_cast<const unsigned int*>(
                Hin + (size_t)e[j].x * NHID + 2 * lane);
#pragma unroll
        for (int j = 0; j < 8; ++j) {
            float v = __builtin_bit_cast(float, e[j].y);
            a0 += v * bflo(h[j]);
            a1 += v * bfhi(h[j]);
        }
    }
    for (; p + 3 < end; p += 4) {
        int2 e[4];
        unsigned int h[4];
#pragma unroll
        for (int j = 0; j < 4; ++j) e[j] = ecv[p + j];
#pragma unroll
        for (int j = 0; j < 4; ++j)
            h[j] = *reinterpret_cast<const unsigned int*>(
                Hin + (size_t)e[j].x * NHID + 2 * lane);
#pragma unroll
        for (int j = 0; j < 4; ++j) {
            float v = __builtin_bit_cast(float, e[j].y);
            a0 += v * bflo(h[j]);
            a1 += v * bfhi(h[j]);
        }
    }
    for (; p < end; ++p) {
        int2 e = ecv[p];
        unsigned int h = *reinterpret_cast<const unsigned int*>(
            Hin + (size_t)e.x * NHID + 2 * lane);
        float v = __builtin_bit_cast(float, e.y);
        a0 += v * bflo(h);  a1 += v * bfhi(h);
    }
    {
        float2 bv = *reinterpret_cast<const float2*>(bias + 2 * lane);
        a0 += bv.x;  a1 += bv.y;
    }

    float sum = a0 + a1, sq = a0 * a0 + a1 * a1;
#pragma unroll
    for (int off = 32; off; off >>= 1) {
        sum += __shfl_xor(sum, off);
        sq  += __shfl_xor(sq, off);
    }
    float mu = sum * (1.f / 128.f);
    float var = sq * (1.f / 128.f) - mu * mu;
    float rs = rsqrtf(var + LN_EPS);
    float2 gv = *reinterpret_cast<const float2*>(g + 2 * lane);
    float2 bbv = *reinterpret_cast<const float2*>(bb + 2 * lane);
    float r0 = fmaxf((a0 - mu) * rs * gv.x + bbv.x, 0.f);
    float r1 = fmaxf((a1 - mu) * rs * gv.y + bbv.y, 0.f);
    unsigned int o = (unsigned int)f2bf(r0) | ((unsigned int)f2bf(r1) << 16);
    *reinterpret_cast<unsigned int*>(Hout + (size_t)row * NHID + 2 * lane) = o;
}

// ---------------------------------------------------------------------------
// Output: logits = H @ Wout + bout, log_softmax. Grid-stride, Wout staged
// once per block. (Proven, unchanged.)
// ---------------------------------------------------------------------------
#define GOUT 2048
__global__ __launch_bounds__(256) void k_out(
    const unsigned short* __restrict__ H, const float* __restrict__ Wout,
    const float* __restrict__ bout, float* __restrict__ out)
{
    __shared__ float ws[NHID * NCLASS];
    __shared__ float bs[NCLASS];
    __shared__ float hrow[4][NHID];
    for (int i = threadIdx.x; i < NHID * NCLASS; i += 256) ws[i] = Wout[i];
    if (threadIdx.x < NCLASS) bs[threadIdx.x] = bout[threadIdx.x];
    __syncthreads();

    const int w = threadIdx.x >> 6;
    const int lane = threadIdx.x & 63;

    for (int rb = blockIdx.x; rb < N_NODES / 4; rb += GOUT) {
        const int row = rb * 4 + w;
        unsigned int hv = *reinterpret_cast<const unsigned int*>(
            H + (size_t)row * NHID + 2 * lane);
        hrow[w][2 * lane]     = bflo(hv);
        hrow[w][2 * lane + 1] = bfhi(hv);
        float acc = (lane < NCLASS) ? bs[lane] : 0.f;
        if (lane < NCLASS) {
#pragma unroll 8
            for (int k = 0; k < NHID; ++k) acc += hrow[w][k] * ws[k * NCLASS + lane];
        }
        float x = (lane < NCLASS) ? acc : -1e30f;
        float m = x;
#pragma unroll
        for (int off = 32; off; off >>= 1) m = fmaxf(m, __shfl_xor(m, off));
        float e = (lane < NCLASS) ? expf(x - m) : 0.f;
        float se = e;
#pragma unroll
        for (int off = 32; off; off >>= 1) se += __shfl_xor(se, off);
        if (lane < NCLASS) out[(size_t)row * NCLASS + lane] = x - m - logf(se);
    }
}

// ---------------------------------------------------------------------------
extern "C" void kernel_launch(void* const* d_in, const int* in_sizes, int n_in,
                              void* d_out, int out_size, void* d_ws, size_t ws_size,
                              hipStream_t stream)
{
    const float* x    = (const float*)d_in[0];
    const int*   rows = (const int*)  d_in[1];
    const int*   cols = (const int*)  d_in[2];
    const float* vals = (const float*)d_in[3];
    const float* W1   = (const float*)d_in[4];
    const float* b1   = (const float*)d_in[5];
    const float* W2   = (const float*)d_in[6];
    const float* b2   = (const float*)d_in[7];
    const float* W3   = (const float*)d_in[8];
    const float* b3   = (const float*)d_in[9];
    const float* ln_g = (const float*)d_in[10];
    const float* ln_b = (const float*)d_in[11];
    const float* Wout = (const float*)d_in[12];
    const float* bout = (const float*)d_in[13];
    float* out = (float*)d_out;

    // workspace layout (16B-aligned blocks first)
    unsigned short* HA16 = (unsigned short*)d_ws;                 // N*128 bf16
    unsigned short* HB16 = HA16 + (size_t)N_NODES * NHID;         // N*128 bf16
    unsigned short* Wf1  = HB16 + (size_t)N_NODES * NHID;
    unsigned short* Wf2  = Wf1 + (size_t)NT1 * 4096;
    unsigned short* Wf3  = Wf2 + (size_t)NT2 * 4096;
    intx4* stage  = (intx4*)(Wf3 + (size_t)NT2 * 4096);           // 24*CAP_G*16B
    int2* ecv3    = (int2*)(stage + (size_t)24 * CAP_G);          // 3*N*DCAP*8B
    int* fill3    = (int*)(ecv3 + (size_t)3 * N_NODES * DCAP);    // 3N
    int* cntA     = fill3 + 3 * N_NODES;                          // 24

    const int gGemm = (N_NODES + 63) / 64;                        // 1563
    const int gRow = N_NODES / 4;                                 // 25000

    // ---- padded-CSR build ----
    k_zero<<<(3 * N_NODES + 24 + 255) / 256, 256, 0, stream>>>(fill3, 3 * N_NODES + 24);
    k_partition<<<3 * BPG, 256, 0, stream>>>(rows, cols, vals, cntA, stage);
    for (int g = 0; g < 3; ++g) {
        k_scatter_l2<<<NBUCK * SLICES, 256, 0, stream>>>(
            stage + (size_t)g * NBUCK * CAP_G, cntA + g * NBUCK,
            fill3 + g * N_NODES, ecv3 + (size_t)g * N_NODES * DCAP);
    }

    // ---- weight pre-swizzle (1 launch) ----
    k_prep_all<<<((NT1 + 2 * NT2) * 8 + 3) / 4, 256, 0, stream>>>(
        W1, W2, W3, Wf1, Wf2, Wf3);

    // ---- layer 1 ----
    k_gemm_slab<NFEAT, false><<<gGemm, 512, 0, stream>>>(x, Wf1, HA16, N_NODES);
    k_spmm_ln<<<gRow, 256, 0, stream>>>(HA16, fill3, ecv3,
                                        b1, ln_g, ln_b, HB16);
    // ---- layer 2 ----
    k_gemm_slab<NHID, true><<<gGemm, 512, 0, stream>>>(HB16, Wf2, HA16, N_NODES);
    k_spmm_ln<<<gRow, 256, 0, stream>>>(HA16, fill3 + N_NODES,
                                        ecv3 + (size_t)N_NODES * DCAP,
                                        b2, ln_g, ln_b, HB16);
    // ---- layer 3 ----
    k_gemm_slab<NHID, true><<<gGemm, 512, 0, stream>>>(HB16, Wf3, HA16, N_NODES);
    k_spmm_ln<<<gRow, 256, 0, stream>>>(HA16, fill3 + 2 * N_NODES,
                                        ecv3 + (size_t)2 * N_NODES * DCAP,
                                        b3, ln_g, ln_b, HB16);
    // ---- output ----
    k_out<<<GOUT, 256, 0, stream>>>(HB16, Wout, bout, out);
}

// Round 16
// 682.731 us; speedup vs baseline: 1.0740x; 1.0740x over previous
//
#include <hip/hip_runtime.h>
#include <cstddef>

#define N_NODES 100000
#define E_EDGES 1600000
#define NFEAT   602
#define NHID    128
#define NCLASS  41
#define LN_EPS  1e-5f

typedef __bf16 bf16x8 __attribute__((ext_vector_type(8)));
typedef float f32x4 __attribute__((ext_vector_type(4)));
typedef unsigned short ushort8 __attribute__((ext_vector_type(8)));
typedef int intx4 __attribute__((ext_vector_type(4)));
typedef float fltx4 __attribute__((ext_vector_type(4)));

__device__ inline float bflo(unsigned int u) {
    return __builtin_bit_cast(float, u << 16);
}
__device__ inline float bfhi(unsigned int u) {
    return __builtin_bit_cast(float, u & 0xFFFF0000u);
}
__device__ inline unsigned short f2bf(float f) {
    return __builtin_bit_cast(unsigned short, (__bf16)f);
}

#define NT1 19   // ceil(602/32)
#define NT2 4    // 128/32

// ---------------------------------------------------------------------------
// Pre-swizzle all three W matrices into MFMA B-fragment layout (bf16).
// ---------------------------------------------------------------------------
__global__ __launch_bounds__(256) void k_prep_all(
    const float* __restrict__ W1, const float* __restrict__ W2,
    const float* __restrict__ W3, unsigned short* __restrict__ Wf1,
    unsigned short* __restrict__ Wf2, unsigned short* __restrict__ Wf3)
{
    const int wid = (blockIdx.x * 256 + threadIdx.x) >> 6;
    const int lane = threadIdx.x & 63;
    const float* W; unsigned short* Wf; int K; int lw;
    if (wid < NT1 * 8)            { W = W1; Wf = Wf1; K = NFEAT; lw = wid; }
    else if (wid < (NT1 + NT2) * 8) { W = W2; Wf = Wf2; K = NHID; lw = wid - NT1 * 8; }
    else if (wid < (NT1 + 2 * NT2) * 8) { W = W3; Wf = Wf3; K = NHID; lw = wid - (NT1 + NT2) * 8; }
    else return;
    const int t = lw >> 3, n = lw & 7;
    const int fr = lane & 15, kh = lane >> 4;
    const int c = n * 16 + fr;
    ushort8 v;
#pragma unroll
    for (int j = 0; j < 8; ++j) {
        int k = t * 32 + kh * 8 + j;
        float x = (k < K) ? W[(size_t)k * 128 + c] : 0.f;
        v[j] = f2bf(x);
    }
    *reinterpret_cast<ushort8*>(Wf + ((size_t)lw * 64 + lane) * 8) = v;
}

// ---------------------------------------------------------------------------
// Slab GEMM: 512 threads stage a contiguous 64-row slab into LDS; 8 waves
// compute 16 rows x 64 cols each. (Proven, unchanged.)
// ---------------------------------------------------------------------------
template<int KK, bool BF16A>
__global__ __launch_bounds__(512) void k_gemm_slab(
    const void* __restrict__ Ain, const unsigned short* __restrict__ Wfrag,
    unsigned short* __restrict__ C, int M)
{
    constexpr int NT = (KK + 31) / 32;
    constexpr int KPAD = ((KK + 7) / 8) * 8 + 8;
    __shared__ unsigned short As[64 * KPAD + 8];

    const int tid = threadIdx.x;
    const int row0 = blockIdx.x * 64;
    const int nrow = (M - row0 < 64) ? (M - row0) : 64;
    const int total = nrow * KK;

    if (!BF16A) {
        const float* A32 = (const float*)Ain + (size_t)row0 * KK;
        constexpr int totalFull = 64 * KK;
#pragma unroll 4
        for (int base = 0; base < totalFull; base += 2048) {
            int i = base + tid * 4;
            if (i < totalFull) {
                float4 v = make_float4(0.f, 0.f, 0.f, 0.f);
                if (i + 4 <= total) {
                    v = *reinterpret_cast<const float4*>(A32 + i);
                } else if (i < total) {
                    float tmp[4] = {0.f, 0.f, 0.f, 0.f};
#pragma unroll
                    for (int e = 0; e < 4; ++e) if (i + e < total) tmp[e] = A32[i + e];
                    v = make_float4(tmp[0], tmp[1], tmp[2], tmp[3]);
                }
                int row = i / KK;
                int col = i - row * KK;
                unsigned int d0 = (unsigned int)f2bf(v.x) | ((unsigned int)f2bf(v.y) << 16);
                unsigned int d1 = (unsigned int)f2bf(v.z) | ((unsigned int)f2bf(v.w) << 16);
                int a0 = row * KPAD + col;
                int a1 = (col == KK - 2) ? (row + 1) * KPAD : a0 + 2;
                *reinterpret_cast<unsigned int*>(&As[a0]) = d0;
                *reinterpret_cast<unsigned int*>(&As[a1]) = d1;
            }
        }
    } else {
        const unsigned short* A16 = (const unsigned short*)Ain + (size_t)row0 * KK;
        constexpr int totalFull = 64 * KK;
#pragma unroll
        for (int base = 0; base < totalFull; base += 4096) {
            int i = base + tid * 8;
            if (i < totalFull) {
                ushort8 v;
#pragma unroll
                for (int j = 0; j < 8; ++j) v[j] = 0;
                if (i + 8 <= total) v = *reinterpret_cast<const ushort8*>(A16 + i);
                int row = i / KK;
                int col = i - row * KK;
                *reinterpret_cast<ushort8*>(&As[row * KPAD + col]) = v;
            }
        }
    }
    __syncthreads();

    const int wv = tid >> 6, lane = tid & 63;
    const int fr = lane & 15, kh = lane >> 4;
    const int mfr = wv >> 1;
    const int ch = wv & 1;
    const unsigned short* abase = &As[(mfr * 16 + fr) * KPAD + kh * 8];
    const unsigned short* wbase = Wfrag + ((size_t)(ch * 4) * 64 + lane) * 8;

    f32x4 acc[4];
#pragma unroll
    for (int n = 0; n < 4; ++n) acc[n] = (f32x4)(0.f);

    bf16x8 bcur[4];
#pragma unroll
    for (int n = 0; n < 4; ++n)
        bcur[n] = __builtin_bit_cast(bf16x8,
            *reinterpret_cast<const ushort8*>(wbase + n * 512));

#pragma unroll
    for (int t = 0; t < NT; ++t) {
        bf16x8 bnext[4];
        if (t + 1 < NT) {
            const unsigned short* wp = wbase + (size_t)(t + 1) * 4096;
#pragma unroll
            for (int n = 0; n < 4; ++n)
                bnext[n] = __builtin_bit_cast(bf16x8,
                    *reinterpret_cast<const ushort8*>(wp + n * 512));
        }
        bf16x8 af = *reinterpret_cast<const bf16x8*>(abase + t * 32);
        if (KK % 32 != 0 && t == NT - 1) {
#pragma unroll
            for (int j = 0; j < 8; ++j)
                if (t * 32 + kh * 8 + j >= KK) af[j] = (__bf16)0.f;
        }
#pragma unroll
        for (int n = 0; n < 4; ++n)
            acc[n] = __builtin_amdgcn_mfma_f32_16x16x32_bf16(af, bcur[n], acc[n], 0, 0, 0);
#pragma unroll
        for (int n = 0; n < 4; ++n) bcur[n] = bnext[n];
    }

#pragma unroll
    for (int jj = 0; jj < 4; ++jj) {
        int cr = row0 + mfr * 16 + kh * 4 + jj;
        if (cr < M) {
#pragma unroll
            for (int n = 0; n < 4; ++n)
                C[(size_t)cr * NHID + ch * 64 + n * 16 + fr] = f2bf(acc[n][jj]);
        }
    }
}

// ---------------------------------------------------------------------------
// Padded-CSR build: partition (no histogram) + per-graph padded scatter.
// Row r owns slots [r*DCAP, r*DCAP+fill[r]).
// ---------------------------------------------------------------------------
__global__ void k_zero(int* __restrict__ p, int n)
{
    int i = blockIdx.x * blockDim.x + threadIdx.x;
    if (i < n) p[i] = 0;
}

#define NBUCK 8
#define RPB   12500        // rows per bucket
#define CAP_G 210000       // stage capacity per (graph,bucket)
#define DCAP  48           // padded slots per row; P(deg>48) ~ 2e-11/row

// Phase A: LDS-binned partition (R14-proven structure; simple LDS atomics —
// R15 showed ballot aggregation regresses). NEW: 4 edges/thread via
// nontemporal intx4/fltx4 loads (chunk sizes are multiples of 4), quartering
// wave count and quadrupling bytes/load-instruction.
#define PCHUNK 3072
#define BPG    ((E_EDGES + PCHUNK - 1) / PCHUNK)   // 521
#define BCAP   512

__global__ __launch_bounds__(256) void k_partition(
    const int* __restrict__ rows, const int* __restrict__ cols,
    const float* __restrict__ vals,
    int* __restrict__ cntA, intx4* __restrict__ stage)
{
    __shared__ int br[NBUCK * BCAP];
    __shared__ int bc[NBUCK * BCAP];
    __shared__ int bv[NBUCK * BCAP];
    __shared__ int bcnt[NBUCK];
    __shared__ int bbase[NBUCK];

    const int g = blockIdx.x / BPG;
    const int chunk = blockIdx.x - g * BPG;
    const int e0 = chunk * PCHUNK;
    const int e1 = (e0 + PCHUNK < E_EDGES) ? (e0 + PCHUNK) : E_EDGES;
    const intx4* rg4 = reinterpret_cast<const intx4*>(rows + (size_t)g * E_EDGES);
    const intx4* cg4 = reinterpret_cast<const intx4*>(cols + (size_t)g * E_EDGES);
    const fltx4* vg4 = reinterpret_cast<const fltx4*>(vals + (size_t)g * E_EDGES);
    const int q0 = e0 >> 2, q1 = e1 >> 2;   // int4 units (chunks mult of 4)

    if (threadIdx.x < NBUCK) bcnt[threadIdx.x] = 0;
    __syncthreads();

    for (int i = q0 + (int)threadIdx.x; i < q1; i += 256) {
        intx4 r4 = __builtin_nontemporal_load(rg4 + i);
        intx4 c4 = __builtin_nontemporal_load(cg4 + i);
        fltx4 v4 = __builtin_nontemporal_load(vg4 + i);
#pragma unroll
        for (int u = 0; u < 4; ++u) {
            int r = r4[u];
            int c = c4[u];
            float v = v4[u];
            int b = r / RPB;
            int off = atomicAdd(&bcnt[b], 1);          // LDS atomic
            if (off < BCAP) {
                br[b * BCAP + off] = r;
                bc[b * BCAP + off] = c;
                bv[b * BCAP + off] = __builtin_bit_cast(int, v);
            } else {                                   // rare overflow
                int p = atomicAdd(&cntA[g * NBUCK + b], 1);
                intx4 e;
                e.x = r; e.y = c; e.z = __builtin_bit_cast(int, v); e.w = 0;
                stage[(size_t)(g * NBUCK + b) * CAP_G + p] = e;
            }
        }
    }
    __syncthreads();

    if (threadIdx.x < NBUCK) {
        int n = bcnt[threadIdx.x];
        n = (n < BCAP) ? n : BCAP;
        bbase[threadIdx.x] = atomicAdd(&cntA[g * NBUCK + threadIdx.x], n);
        bcnt[threadIdx.x] = n;
    }
    __syncthreads();

#pragma unroll
    for (int b = 0; b < NBUCK; ++b) {
        int n = bcnt[b];
        int base = bbase[b];
        intx4* dst = stage + (size_t)(g * NBUCK + b) * CAP_G;
        for (int j = (int)threadIdx.x; j < n; j += 256) {
            intx4 e;
            e.x = br[b * BCAP + j];
            e.y = bc[b * BCAP + j];
            e.z = bv[b * BCAP + j];
            e.w = 0;
            dst[base + j] = e;
        }
    }
}

#define SLICES 256

// Phase B: per-graph padded scatter (proven). bucket = blockIdx&7 (XCD pin).
// fill[r] counts edges AND assigns the slot: ecv[r*DCAP + p].
__global__ __launch_bounds__(256) void k_scatter_l2(
    const intx4* __restrict__ stageG,   // stage + g*8*CAP_G
    const int* __restrict__ cntAG,      // cntA + g*8
    int* __restrict__ fillG,            // fill3 + g*N
    int2* __restrict__ ecvG)            // ecv3 + g*N*DCAP
{
    const int b = blockIdx.x & 7;
    const int slice = blockIdx.x >> 3;
    const int n = cntAG[b];
    const intx4* sp = stageG + (size_t)b * CAP_G;
    for (int i = slice * 256 + (int)threadIdx.x; i < n; i += SLICES * 256) {
        intx4 e = __builtin_nontemporal_load(sp + i);
        int p = atomicAdd(&fillG[e.x], 1);
        if (p < DCAP)
            ecvG[(size_t)e.x * DCAP + p] = make_int2(e.y, e.z);
    }
}

// ---------------------------------------------------------------------------
// Fused spmm (padded CSR gather, bf16 H) + bias + LayerNorm + ReLU.
// Row r's edges at [r*DCAP, r*DCAP + fill[r]). Unroll 8 (proven body).
// ---------------------------------------------------------------------------
__global__ __launch_bounds__(256) void k_spmm_ln(
    const unsigned short* __restrict__ Hin, const int* __restrict__ fillG,
    const int2* __restrict__ ecvG,
    const float* __restrict__ bias, const float* __restrict__ g,
    const float* __restrict__ bb, unsigned short* __restrict__ Hout)
{
    const int w = threadIdx.x >> 6;
    const int lane = threadIdx.x & 63;
    const int row = blockIdx.x * 4 + w;
    int cnt = fillG[row];
    cnt = (cnt < DCAP) ? cnt : DCAP;
    const int start = row * DCAP;
    const int end = start + cnt;
    const int2* ecv = ecvG;

    float a0 = 0.f, a1 = 0.f;
    int p = start;
    for (; p + 7 < end; p += 8) {
        int2 e[8];
        unsigned int h[8];
#pragma unroll
        for (int j = 0; j < 8; ++j) e[j] = ecv[p + j];
#pragma unroll
        for (int j = 0; j < 8; ++j)
            h[j] = *reinterpret_cast<const unsigned int*>(
                Hin + (size_t)e[j].x * NHID + 2 * lane);
#pragma unroll
        for (int j = 0; j < 8; ++j) {
            float v = __builtin_bit_cast(float, e[j].y);
            a0 += v * bflo(h[j]);
            a1 += v * bfhi(h[j]);
        }
    }
    for (; p + 3 < end; p += 4) {
        int2 e[4];
        unsigned int h[4];
#pragma unroll
        for (int j = 0; j < 4; ++j) e[j] = ecv[p + j];
#pragma unroll
        for (int j = 0; j < 4; ++j)
            h[j] = *reinterpret_cast<const unsigned int*>(
                Hin + (size_t)e[j].x * NHID + 2 * lane);
#pragma unroll
        for (int j = 0; j < 4; ++j) {
            float v = __builtin_bit_cast(float, e[j].y);
            a0 += v * bflo(h[j]);
            a1 += v * bfhi(h[j]);
        }
    }
    for (; p < end; ++p) {
        int2 e = ecv[p];
        unsigned int h = *reinterpret_cast<const unsigned int*>(
            Hin + (size_t)e.x * NHID + 2 * lane);
        float v = __builtin_bit_cast(float, e.y);
        a0 += v * bflo(h);  a1 += v * bfhi(h);
    }
    {
        float2 bv = *reinterpret_cast<const float2*>(bias + 2 * lane);
        a0 += bv.x;  a1 += bv.y;
    }

    float sum = a0 + a1, sq = a0 * a0 + a1 * a1;
#pragma unroll
    for (int off = 32; off; off >>= 1) {
        sum += __shfl_xor(sum, off);
        sq  += __shfl_xor(sq, off);
    }
    float mu = sum * (1.f / 128.f);
    float var = sq * (1.f / 128.f) - mu * mu;
    float rs = rsqrtf(var + LN_EPS);
    float2 gv = *reinterpret_cast<const float2*>(g + 2 * lane);
    float2 bbv = *reinterpret_cast<const float2*>(bb + 2 * lane);
    float r0 = fmaxf((a0 - mu) * rs * gv.x + bbv.x, 0.f);
    float r1 = fmaxf((a1 - mu) * rs * gv.y + bbv.y, 0.f);
    unsigned int o = (unsigned int)f2bf(r0) | ((unsigned int)f2bf(r1) << 16);
    *reinterpret_cast<unsigned int*>(Hout + (size_t)row * NHID + 2 * lane) = o;
}

// ---------------------------------------------------------------------------
// Output: logits = H @ Wout + bout, log_softmax. Grid-stride, Wout staged
// once per block. (Proven, unchanged.)
// ---------------------------------------------------------------------------
#define GOUT 2048
__global__ __launch_bounds__(256) void k_out(
    const unsigned short* __restrict__ H, const float* __restrict__ Wout,
    const float* __restrict__ bout, float* __restrict__ out)
{
    __shared__ float ws[NHID * NCLASS];
    __shared__ float bs[NCLASS];
    __shared__ float hrow[4][NHID];
    for (int i = threadIdx.x; i < NHID * NCLASS; i += 256) ws[i] = Wout[i];
    if (threadIdx.x < NCLASS) bs[threadIdx.x] = bout[threadIdx.x];
    __syncthreads();

    const int w = threadIdx.x >> 6;
    const int lane = threadIdx.x & 63;

    for (int rb = blockIdx.x; rb < N_NODES / 4; rb += GOUT) {
        const int row = rb * 4 + w;
        unsigned int hv = *reinterpret_cast<const unsigned int*>(
            H + (size_t)row * NHID + 2 * lane);
        hrow[w][2 * lane]     = bflo(hv);
        hrow[w][2 * lane + 1] = bfhi(hv);
        float acc = (lane < NCLASS) ? bs[lane] : 0.f;
        if (lane < NCLASS) {
#pragma unroll 8
            for (int k = 0; k < NHID; ++k) acc += hrow[w][k] * ws[k * NCLASS + lane];
        }
        float x = (lane < NCLASS) ? acc : -1e30f;
        float m = x;
#pragma unroll
        for (int off = 32; off; off >>= 1) m = fmaxf(m, __shfl_xor(m, off));
        float e = (lane < NCLASS) ? expf(x - m) : 0.f;
        float se = e;
#pragma unroll
        for (int off = 32; off; off >>= 1) se += __shfl_xor(se, off);
        if (lane < NCLASS) out[(size_t)row * NCLASS + lane] = x - m - logf(se);
    }
}

// ---------------------------------------------------------------------------
extern "C" void kernel_launch(void* const* d_in, const int* in_sizes, int n_in,
                              void* d_out, int out_size, void* d_ws, size_t ws_size,
                              hipStream_t stream)
{
    const float* x    = (const float*)d_in[0];
    const int*   rows = (const int*)  d_in[1];
    const int*   cols = (const int*)  d_in[2];
    const float* vals = (const float*)d_in[3];
    const float* W1   = (const float*)d_in[4];
    const float* b1   = (const float*)d_in[5];
    const float* W2   = (const float*)d_in[6];
    const float* b2   = (const float*)d_in[7];
    const float* W3   = (const float*)d_in[8];
    const float* b3   = (const float*)d_in[9];
    const float* ln_g = (const float*)d_in[10];
    const float* ln_b = (const float*)d_in[11];
    const float* Wout = (const float*)d_in[12];
    const float* bout = (const float*)d_in[13];
    float* out = (float*)d_out;

    // workspace layout (16B-aligned blocks first)
    unsigned short* HA16 = (unsigned short*)d_ws;                 // N*128 bf16
    unsigned short* HB16 = HA16 + (size_t)N_NODES * NHID;         // N*128 bf16
    unsigned short* Wf1  = HB16 + (size_t)N_NODES * NHID;
    unsigned short* Wf2  = Wf1 + (size_t)NT1 * 4096;
    unsigned short* Wf3  = Wf2 + (size_t)NT2 * 4096;
    intx4* stage  = (intx4*)(Wf3 + (size_t)NT2 * 4096);           // 24*CAP_G*16B
    int2* ecv3    = (int2*)(stage + (size_t)24 * CAP_G);          // 3*N*DCAP*8B
    int* fill3    = (int*)(ecv3 + (size_t)3 * N_NODES * DCAP);    // 3N
    int* cntA     = fill3 + 3 * N_NODES;                          // 24

    const int gGemm = (N_NODES + 63) / 64;                        // 1563
    const int gRow = N_NODES / 4;                                 // 25000

    // ---- padded-CSR build ----
    k_zero<<<(3 * N_NODES + 24 + 255) / 256, 256, 0, stream>>>(fill3, 3 * N_NODES + 24);
    k_partition<<<3 * BPG, 256, 0, stream>>>(rows, cols, vals, cntA, stage);
    for (int g = 0; g < 3; ++g) {
        k_scatter_l2<<<NBUCK * SLICES, 256, 0, stream>>>(
            stage + (size_t)g * NBUCK * CAP_G, cntA + g * NBUCK,
            fill3 + g * N_NODES, ecv3 + (size_t)g * N_NODES * DCAP);
    }

    // ---- weight pre-swizzle (1 launch) ----
    k_prep_all<<<((NT1 + 2 * NT2) * 8 + 3) / 4, 256, 0, stream>>>(
        W1, W2, W3, Wf1, Wf2, Wf3);

    // ---- layer 1 ----
    k_gemm_slab<NFEAT, false><<<gGemm, 512, 0, stream>>>(x, Wf1, HA16, N_NODES);
    k_spmm_ln<<<gRow, 256, 0, stream>>>(HA16, fill3, ecv3,
                                        b1, ln_g, ln_b, HB16);
    // ---- layer 2 ----
    k_gemm_slab<NHID, true><<<gGemm, 512, 0, stream>>>(HB16, Wf2, HA16, N_NODES);
    k_spmm_ln<<<gRow, 256, 0, stream>>>(HA16, fill3 + N_NODES,
                                        ecv3 + (size_t)N_NODES * DCAP,
                                        b2, ln_g, ln_b, HB16);
    // ---- layer 3 ----
    k_gemm_slab<NHID, true><<<gGemm, 512, 0, stream>>>(HB16, Wf3, HA16, N_NODES);
    k_spmm_ln<<<gRow, 256, 0, stream>>>(HA16, fill3 + 2 * N_NODES,
                                        ecv3 + (size_t)2 * N_NODES * DCAP,
                                        b3, ln_g, ln_b, HB16);
    // ---- output ----
    k_out<<<GOUT, 256, 0, stream>>>(HB16, Wout, bout, out);
}

// Round 17
// 676.725 us; speedup vs baseline: 1.0835x; 1.0089x over previous
//
#include <hip/hip_runtime.h>
#include <cstddef>

#define N_NODES 100000
#define E_EDGES 1600000
#define NFEAT   602
#define NHID    128
#define NCLASS  41
#define LN_EPS  1e-5f

typedef __bf16 bf16x8 __attribute__((ext_vector_type(8)));
typedef float f32x4 __attribute__((ext_vector_type(4)));
typedef unsigned short ushort8 __attribute__((ext_vector_type(8)));
typedef int intx4 __attribute__((ext_vector_type(4)));
typedef float fltx4 __attribute__((ext_vector_type(4)));

__device__ inline float bflo(unsigned int u) {
    return __builtin_bit_cast(float, u << 16);
}
__device__ inline float bfhi(unsigned int u) {
    return __builtin_bit_cast(float, u & 0xFFFF0000u);
}
__device__ inline unsigned short f2bf(float f) {
    return __builtin_bit_cast(unsigned short, (__bf16)f);
}

#define NT1 19   // ceil(602/32)
#define NT2 4    // 128/32

// ---------------------------------------------------------------------------
// Pre-swizzle all three W matrices into MFMA B-fragment layout (bf16).
// ---------------------------------------------------------------------------
__global__ __launch_bounds__(256) void k_prep_all(
    const float* __restrict__ W1, const float* __restrict__ W2,
    const float* __restrict__ W3, unsigned short* __restrict__ Wf1,
    unsigned short* __restrict__ Wf2, unsigned short* __restrict__ Wf3)
{
    const int wid = (blockIdx.x * 256 + threadIdx.x) >> 6;
    const int lane = threadIdx.x & 63;
    const float* W; unsigned short* Wf; int K; int lw;
    if (wid < NT1 * 8)            { W = W1; Wf = Wf1; K = NFEAT; lw = wid; }
    else if (wid < (NT1 + NT2) * 8) { W = W2; Wf = Wf2; K = NHID; lw = wid - NT1 * 8; }
    else if (wid < (NT1 + 2 * NT2) * 8) { W = W3; Wf = Wf3; K = NHID; lw = wid - (NT1 + NT2) * 8; }
    else return;
    const int t = lw >> 3, n = lw & 7;
    const int fr = lane & 15, kh = lane >> 4;
    const int c = n * 16 + fr;
    ushort8 v;
#pragma unroll
    for (int j = 0; j < 8; ++j) {
        int k = t * 32 + kh * 8 + j;
        float x = (k < K) ? W[(size_t)k * 128 + c] : 0.f;
        v[j] = f2bf(x);
    }
    *reinterpret_cast<ushort8*>(Wf + ((size_t)lw * 64 + lane) * 8) = v;
}

// ---------------------------------------------------------------------------
// Slab GEMM: 512 threads stage a contiguous 64-row slab into LDS; 8 waves
// compute 16 rows x 64 cols each. (Proven, unchanged.)
// ---------------------------------------------------------------------------
template<int KK, bool BF16A>
__global__ __launch_bounds__(512) void k_gemm_slab(
    const void* __restrict__ Ain, const unsigned short* __restrict__ Wfrag,
    unsigned short* __restrict__ C, int M)
{
    constexpr int NT = (KK + 31) / 32;
    constexpr int KPAD = ((KK + 7) / 8) * 8 + 8;
    __shared__ unsigned short As[64 * KPAD + 8];

    const int tid = threadIdx.x;
    const int row0 = blockIdx.x * 64;
    const int nrow = (M - row0 < 64) ? (M - row0) : 64;
    const int total = nrow * KK;

    if (!BF16A) {
        const float* A32 = (const float*)Ain + (size_t)row0 * KK;
        constexpr int totalFull = 64 * KK;
#pragma unroll 4
        for (int base = 0; base < totalFull; base += 2048) {
            int i = base + tid * 4;
            if (i < totalFull) {
                float4 v = make_float4(0.f, 0.f, 0.f, 0.f);
                if (i + 4 <= total) {
                    v = *reinterpret_cast<const float4*>(A32 + i);
                } else if (i < total) {
                    float tmp[4] = {0.f, 0.f, 0.f, 0.f};
#pragma unroll
                    for (int e = 0; e < 4; ++e) if (i + e < total) tmp[e] = A32[i + e];
                    v = make_float4(tmp[0], tmp[1], tmp[2], tmp[3]);
                }
                int row = i / KK;
                int col = i - row * KK;
                unsigned int d0 = (unsigned int)f2bf(v.x) | ((unsigned int)f2bf(v.y) << 16);
                unsigned int d1 = (unsigned int)f2bf(v.z) | ((unsigned int)f2bf(v.w) << 16);
                int a0 = row * KPAD + col;
                int a1 = (col == KK - 2) ? (row + 1) * KPAD : a0 + 2;
                *reinterpret_cast<unsigned int*>(&As[a0]) = d0;
                *reinterpret_cast<unsigned int*>(&As[a1]) = d1;
            }
        }
    } else {
        const unsigned short* A16 = (const unsigned short*)Ain + (size_t)row0 * KK;
        constexpr int totalFull = 64 * KK;
#pragma unroll
        for (int base = 0; base < totalFull; base += 4096) {
            int i = base + tid * 8;
            if (i < totalFull) {
                ushort8 v;
#pragma unroll
                for (int j = 0; j < 8; ++j) v[j] = 0;
                if (i + 8 <= total) v = *reinterpret_cast<const ushort8*>(A16 + i);
                int row = i / KK;
                int col = i - row * KK;
                *reinterpret_cast<ushort8*>(&As[row * KPAD + col]) = v;
            }
        }
    }
    __syncthreads();

    const int wv = tid >> 6, lane = tid & 63;
    const int fr = lane & 15, kh = lane >> 4;
    const int mfr = wv >> 1;
    const int ch = wv & 1;
    const unsigned short* abase = &As[(mfr * 16 + fr) * KPAD + kh * 8];
    const unsigned short* wbase = Wfrag + ((size_t)(ch * 4) * 64 + lane) * 8;

    f32x4 acc[4];
#pragma unroll
    for (int n = 0; n < 4; ++n) acc[n] = (f32x4)(0.f);

    bf16x8 bcur[4];
#pragma unroll
    for (int n = 0; n < 4; ++n)
        bcur[n] = __builtin_bit_cast(bf16x8,
            *reinterpret_cast<const ushort8*>(wbase + n * 512));

#pragma unroll
    for (int t = 0; t < NT; ++t) {
        bf16x8 bnext[4];
        if (t + 1 < NT) {
            const unsigned short* wp = wbase + (size_t)(t + 1) * 4096;
#pragma unroll
            for (int n = 0; n < 4; ++n)
                bnext[n] = __builtin_bit_cast(bf16x8,
                    *reinterpret_cast<const ushort8*>(wp + n * 512));
        }
        bf16x8 af = *reinterpret_cast<const bf16x8*>(abase + t * 32);
        if (KK % 32 != 0 && t == NT - 1) {
#pragma unroll
            for (int j = 0; j < 8; ++j)
                if (t * 32 + kh * 8 + j >= KK) af[j] = (__bf16)0.f;
        }
#pragma unroll
        for (int n = 0; n < 4; ++n)
            acc[n] = __builtin_amdgcn_mfma_f32_16x16x32_bf16(af, bcur[n], acc[n], 0, 0, 0);
#pragma unroll
        for (int n = 0; n < 4; ++n) bcur[n] = bnext[n];
    }

#pragma unroll
    for (int jj = 0; jj < 4; ++jj) {
        int cr = row0 + mfr * 16 + kh * 4 + jj;
        if (cr < M) {
#pragma unroll
            for (int n = 0; n < 4; ++n)
                C[(size_t)cr * NHID + ch * 64 + n * 16 + fr] = f2bf(acc[n][jj]);
        }
    }
}

// ---------------------------------------------------------------------------
// Padded-CSR build: partition (no histogram) + per-graph padded scatter.
// Row r owns slots [r*DCAP, r*DCAP+fill[r]).
// ---------------------------------------------------------------------------
__global__ void k_zero(int* __restrict__ p, int n)
{
    int i = blockIdx.x * blockDim.x + threadIdx.x;
    if (i < n) p[i] = 0;
}

#define NBUCK 8
#define RPB   12500        // rows per bucket
#define CAP_G 210000       // stage capacity per (graph,bucket)
#define DCAP  48           // padded slots per row; P(deg>48) ~ 2e-11/row

// Phase A: LDS-binned partition (proven; 4 edges/thread nontemporal loads).
#define PCHUNK 3072
#define BPG    ((E_EDGES + PCHUNK - 1) / PCHUNK)   // 521
#define BCAP   512

__global__ __launch_bounds__(256) void k_partition(
    const int* __restrict__ rows, const int* __restrict__ cols,
    const float* __restrict__ vals,
    int* __restrict__ cntA, intx4* __restrict__ stage)
{
    __shared__ int br[NBUCK * BCAP];
    __shared__ int bc[NBUCK * BCAP];
    __shared__ int bv[NBUCK * BCAP];
    __shared__ int bcnt[NBUCK];
    __shared__ int bbase[NBUCK];

    const int g = blockIdx.x / BPG;
    const int chunk = blockIdx.x - g * BPG;
    const int e0 = chunk * PCHUNK;
    const int e1 = (e0 + PCHUNK < E_EDGES) ? (e0 + PCHUNK) : E_EDGES;
    const intx4* rg4 = reinterpret_cast<const intx4*>(rows + (size_t)g * E_EDGES);
    const intx4* cg4 = reinterpret_cast<const intx4*>(cols + (size_t)g * E_EDGES);
    const fltx4* vg4 = reinterpret_cast<const fltx4*>(vals + (size_t)g * E_EDGES);
    const int q0 = e0 >> 2, q1 = e1 >> 2;   // int4 units (chunks mult of 4)

    if (threadIdx.x < NBUCK) bcnt[threadIdx.x] = 0;
    __syncthreads();

    for (int i = q0 + (int)threadIdx.x; i < q1; i += 256) {
        intx4 r4 = __builtin_nontemporal_load(rg4 + i);
        intx4 c4 = __builtin_nontemporal_load(cg4 + i);
        fltx4 v4 = __builtin_nontemporal_load(vg4 + i);
#pragma unroll
        for (int u = 0; u < 4; ++u) {
            int r = r4[u];
            int c = c4[u];
            float v = v4[u];
            int b = r / RPB;
            int off = atomicAdd(&bcnt[b], 1);          // LDS atomic
            if (off < BCAP) {
                br[b * BCAP + off] = r;
                bc[b * BCAP + off] = c;
                bv[b * BCAP + off] = __builtin_bit_cast(int, v);
            } else {                                   // rare overflow
                int p = atomicAdd(&cntA[g * NBUCK + b], 1);
                intx4 e;
                e.x = r; e.y = c; e.z = __builtin_bit_cast(int, v); e.w = 0;
                stage[(size_t)(g * NBUCK + b) * CAP_G + p] = e;
            }
        }
    }
    __syncthreads();

    if (threadIdx.x < NBUCK) {
        int n = bcnt[threadIdx.x];
        n = (n < BCAP) ? n : BCAP;
        bbase[threadIdx.x] = atomicAdd(&cntA[g * NBUCK + threadIdx.x], n);
        bcnt[threadIdx.x] = n;
    }
    __syncthreads();

#pragma unroll
    for (int b = 0; b < NBUCK; ++b) {
        int n = bcnt[b];
        int base = bbase[b];
        intx4* dst = stage + (size_t)(g * NBUCK + b) * CAP_G;
        for (int j = (int)threadIdx.x; j < n; j += 256) {
            intx4 e;
            e.x = br[b * BCAP + j];
            e.y = bc[b * BCAP + j];
            e.z = bv[b * BCAP + j];
            e.w = 0;
            dst[base + j] = e;
        }
    }
}

#define SLICES 256

// Phase B: per-graph padded scatter (proven). bucket = blockIdx&7 (XCD pin).
__global__ __launch_bounds__(256) void k_scatter_l2(
    const intx4* __restrict__ stageG,   // stage + g*8*CAP_G
    const int* __restrict__ cntAG,      // cntA + g*8
    int* __restrict__ fillG,            // fill3 + g*N
    int2* __restrict__ ecvG)            // ecv3 + g*N*DCAP
{
    const int b = blockIdx.x & 7;
    const int slice = blockIdx.x >> 3;
    const int n = cntAG[b];
    const intx4* sp = stageG + (size_t)b * CAP_G;
    for (int i = slice * 256 + (int)threadIdx.x; i < n; i += SLICES * 256) {
        intx4 e = __builtin_nontemporal_load(sp + i);
        int p = atomicAdd(&fillG[e.x], 1);
        if (p < DCAP)
            ecvG[(size_t)e.x * DCAP + p] = make_int2(e.y, e.z);
    }
}

// ---------------------------------------------------------------------------
// Fused spmm (padded CSR gather, bf16 H) + bias + LayerNorm + ReLU.
// NEW: unroll 16 (16 outstanding 256B gathers/wave to probe the MLP limit).
// ---------------------------------------------------------------------------
__global__ __launch_bounds__(256) void k_spmm_ln(
    const unsigned short* __restrict__ Hin, const int* __restrict__ fillG,
    const int2* __restrict__ ecvG,
    const float* __restrict__ bias, const float* __restrict__ g,
    const float* __restrict__ bb, unsigned short* __restrict__ Hout)
{
    const int w = threadIdx.x >> 6;
    const int lane = threadIdx.x & 63;
    const int row = blockIdx.x * 4 + w;
    int cnt = fillG[row];
    cnt = (cnt < DCAP) ? cnt : DCAP;
    const int start = row * DCAP;
    const int end = start + cnt;
    const int2* ecv = ecvG;

    float a0 = 0.f, a1 = 0.f;
    int p = start;
    for (; p + 15 < end; p += 16) {
        int2 e[16];
        unsigned int h[16];
#pragma unroll
        for (int j = 0; j < 16; ++j) e[j] = ecv[p + j];
#pragma unroll
        for (int j = 0; j < 16; ++j)
            h[j] = *reinterpret_cast<const unsigned int*>(
                Hin + (size_t)e[j].x * NHID + 2 * lane);
#pragma unroll
        for (int j = 0; j < 16; ++j) {
            float v = __builtin_bit_cast(float, e[j].y);
            a0 += v * bflo(h[j]);
            a1 += v * bfhi(h[j]);
        }
    }
    for (; p + 7 < end; p += 8) {
        int2 e[8];
        unsigned int h[8];
#pragma unroll
        for (int j = 0; j < 8; ++j) e[j] = ecv[p + j];
#pragma unroll
        for (int j = 0; j < 8; ++j)
            h[j] = *reinterpret_cast<const unsigned int*>(
                Hin + (size_t)e[j].x * NHID + 2 * lane);
#pragma unroll
        for (int j = 0; j < 8; ++j) {
            float v = __builtin_bit_cast(float, e[j].y);
            a0 += v * bflo(h[j]);
            a1 += v * bfhi(h[j]);
        }
    }
    for (; p + 3 < end; p += 4) {
        int2 e[4];
        unsigned int h[4];
#pragma unroll
        for (int j = 0; j < 4; ++j) e[j] = ecv[p + j];
#pragma unroll
        for (int j = 0; j < 4; ++j)
            h[j] = *reinterpret_cast<const unsigned int*>(
                Hin + (size_t)e[j].x * NHID + 2 * lane);
#pragma unroll
        for (int j = 0; j < 4; ++j) {
            float v = __builtin_bit_cast(float, e[j].y);
            a0 += v * bflo(h[j]);
            a1 += v * bfhi(h[j]);
        }
    }
    for (; p < end; ++p) {
        int2 e = ecv[p];
        unsigned int h = *reinterpret_cast<const unsigned int*>(
            Hin + (size_t)e.x * NHID + 2 * lane);
        float v = __builtin_bit_cast(float, e.y);
        a0 += v * bflo(h);  a1 += v * bfhi(h);
    }
    {
        float2 bv = *reinterpret_cast<const float2*>(bias + 2 * lane);
        a0 += bv.x;  a1 += bv.y;
    }

    float sum = a0 + a1, sq = a0 * a0 + a1 * a1;
#pragma unroll
    for (int off = 32; off; off >>= 1) {
        sum += __shfl_xor(sum, off);
        sq  += __shfl_xor(sq, off);
    }
    float mu = sum * (1.f / 128.f);
    float var = sq * (1.f / 128.f) - mu * mu;
    float rs = rsqrtf(var + LN_EPS);
    float2 gv = *reinterpret_cast<const float2*>(g + 2 * lane);
    float2 bbv = *reinterpret_cast<const float2*>(bb + 2 * lane);
    float r0 = fmaxf((a0 - mu) * rs * gv.x + bbv.x, 0.f);
    float r1 = fmaxf((a1 - mu) * rs * gv.y + bbv.y, 0.f);
    unsigned int o = (unsigned int)f2bf(r0) | ((unsigned int)f2bf(r1) << 16);
    *reinterpret_cast<unsigned int*>(Hout + (size_t)row * NHID + 2 * lane) = o;
}

// ---------------------------------------------------------------------------
// Output: logits = H @ Wout + bout, log_softmax. Grid-stride, Wout staged
// once per block. (Proven, unchanged.)
// ---------------------------------------------------------------------------
#define GOUT 2048
__global__ __launch_bounds__(256) void k_out(
    const unsigned short* __restrict__ H, const float* __restrict__ Wout,
    const float* __restrict__ bout, float* __restrict__ out)
{
    __shared__ float ws[NHID * NCLASS];
    __shared__ float bs[NCLASS];
    __shared__ float hrow[4][NHID];
    for (int i = threadIdx.x; i < NHID * NCLASS; i += 256) ws[i] = Wout[i];
    if (threadIdx.x < NCLASS) bs[threadIdx.x] = bout[threadIdx.x];
    __syncthreads();

    const int w = threadIdx.x >> 6;
    const int lane = threadIdx.x & 63;

    for (int rb = blockIdx.x; rb < N_NODES / 4; rb += GOUT) {
        const int row = rb * 4 + w;
        unsigned int hv = *reinterpret_cast<const unsigned int*>(
            H + (size_t)row * NHID + 2 * lane);
        hrow[w][2 * lane]     = bflo(hv);
        hrow[w][2 * lane + 1] = bfhi(hv);
        float acc = (lane < NCLASS) ? bs[lane] : 0.f;
        if (lane < NCLASS) {
#pragma unroll 8
            for (int k = 0; k < NHID; ++k) acc += hrow[w][k] * ws[k * NCLASS + lane];
        }
        float x = (lane < NCLASS) ? acc : -1e30f;
        float m = x;
#pragma unroll
        for (int off = 32; off; off >>= 1) m = fmaxf(m, __shfl_xor(m, off));
        float e = (lane < NCLASS) ? expf(x - m) : 0.f;
        float se = e;
#pragma unroll
        for (int off = 32; off; off >>= 1) se += __shfl_xor(se, off);
        if (lane < NCLASS) out[(size_t)row * NCLASS + lane] = x - m - logf(se);
    }
}

// ---------------------------------------------------------------------------
extern "C" void kernel_launch(void* const* d_in, const int* in_sizes, int n_in,
                              void* d_out, int out_size, void* d_ws, size_t ws_size,
                              hipStream_t stream)
{
    const float* x    = (const float*)d_in[0];
    const int*   rows = (const int*)  d_in[1];
    const int*   cols = (const int*)  d_in[2];
    const float* vals = (const float*)d_in[3];
    const float* W1   = (const float*)d_in[4];
    const float* b1   = (const float*)d_in[5];
    const float* W2   = (const float*)d_in[6];
    const float* b2   = (const float*)d_in[7];
    const float* W3   = (const float*)d_in[8];
    const float* b3   = (const float*)d_in[9];
    const float* ln_g = (const float*)d_in[10];
    const float* ln_b = (const float*)d_in[11];
    const float* Wout = (const float*)d_in[12];
    const float* bout = (const float*)d_in[13];
    float* out = (float*)d_out;

    // workspace layout (16B-aligned blocks first)
    unsigned short* HA16 = (unsigned short*)d_ws;                 // N*128 bf16
    unsigned short* HB16 = HA16 + (size_t)N_NODES * NHID;         // N*128 bf16
    unsigned short* Wf1  = HB16 + (size_t)N_NODES * NHID;
    unsigned short* Wf2  = Wf1 + (size_t)NT1 * 4096;
    unsigned short* Wf3  = Wf2 + (size_t)NT2 * 4096;
    intx4* stage  = (intx4*)(Wf3 + (size_t)NT2 * 4096);           // 24*CAP_G*16B
    int2* ecv3    = (int2*)(stage + (size_t)24 * CAP_G);          // 3*N*DCAP*8B
    int* fill3    = (int*)(ecv3 + (size_t)3 * N_NODES * DCAP);    // 3N
    int* cntA     = fill3 + 3 * N_NODES;                          // 24

    const int gGemm = (N_NODES + 63) / 64;                        // 1563
    const int gRow = N_NODES / 4;                                 // 25000

    // ---- padded-CSR build ----
    k_zero<<<(3 * N_NODES + 24 + 255) / 256, 256, 0, stream>>>(fill3, 3 * N_NODES + 24);
    k_partition<<<3 * BPG, 256, 0, stream>>>(rows, cols, vals, cntA, stage);
    for (int g = 0; g < 3; ++g) {
        k_scatter_l2<<<NBUCK * SLICES, 256, 0, stream>>>(
            stage + (size_t)g * NBUCK * CAP_G, cntA + g * NBUCK,
            fill3 + g * N_NODES, ecv3 + (size_t)g * N_NODES * DCAP);
    }

    // ---- weight pre-swizzle (1 launch) ----
    k_prep_all<<<((NT1 + 2 * NT2) * 8 + 3) / 4, 256, 0, stream>>>(
        W1, W2, W3, Wf1, Wf2, Wf3);

    // ---- layer 1 ----
    k_gemm_slab<NFEAT, false><<<gGemm, 512, 0, stream>>>(x, Wf1, HA16, N_NODES);
    k_spmm_ln<<<gRow, 256, 0, stream>>>(HA16, fill3, ecv3,
                                        b1, ln_g, ln_b, HB16);
    // ---- layer 2 ----
    k_gemm_slab<NHID, true><<<gGemm, 512, 0, stream>>>(HB16, Wf2, HA16, N_NODES);
    k_spmm_ln<<<gRow, 256, 0, stream>>>(HA16, fill3 + N_NODES,
                                        ecv3 + (size_t)N_NODES * DCAP,
                                        b2, ln_g, ln_b, HB16);
    // ---- layer 3 ----
    k_gemm_slab<NHID, true><<<gGemm, 512, 0, stream>>>(HB16, Wf3, HA16, N_NODES);
    k_spmm_ln<<<gRow, 256, 0, stream>>>(HA16, fill3 + 2 * N_NODES,
                                        ecv3 + (size_t)2 * N_NODES * DCAP,
                                        b3, ln_g, ln_b, HB16);
    // ---- output ----
    k_out<<<GOUT, 256, 0, stream>>>(HB16, Wout, bout, out);
}